// Round 3
// baseline (139.359 us; speedup 1.0000x reference)
//
#include <hip/hip_runtime.h>
#include <hip/hip_cooperative_groups.h>
#include <math.h>

namespace cg = cooperative_groups;

#define BSZ 320
#define N2  640
#define DIM 128
#define GAM (1.0/0.07)

__device__ __forceinline__ double wave_red(double v) {
    #pragma unroll
    for (int off = 32; off > 0; off >>= 1) v += __shfl_down(v, off, 64);
    return v;
}

__launch_bounds__(320)
__global__ void k_all(const float* __restrict__ z, float* __restrict__ znT,
                      float* __restrict__ znR, double* __restrict__ KnT,
                      double* __restrict__ rE, double* __restrict__ posterm,
                      double* __restrict__ partials, float* __restrict__ out) {
    cg::grid_group grid = cg::this_grid();
    const int t   = blockIdx.x;    // 320
    const int tid = threadIdx.x;   // 320
    const int wave = tid >> 6, lane = tid & 63;

    __shared__ double sred[5][8];
    __shared__ double sc[8];
    __shared__ float  zi[DIM];

    // ---------- Phase 1: normalize rows 2t and 2t+1 (f64 norm -> f32) ----------
    {
        int r = tid >> 7, k = tid & 127;        // threads 0..255 active
        double v = 0.0;
        if (tid < 256) v = (double)z[(2 * t + r) * DIM + k];
        double w = wave_red(v * v);
        if (lane == 0) sred[wave][0] = w;
        __syncthreads();
        if (tid < 256) {
            double tot = sred[2 * r][0] + sred[2 * r + 1][0];
            float zn = (float)(v / sqrt(tot));
            znT[k * N2 + (2 * t + r)] = zn;
            znR[(2 * t + r) * DIM + k] = zn;
        }
    }
    grid.sync();

    // ---------- Phase 2: row t of gram; E[t][tid] stays in register ----------
    if (tid < DIM) zi[tid] = znR[t * DIM + tid];
    __syncthreads();
    float c0 = 0.f, c1 = 0.f;
    #pragma unroll 8
    for (int k = 0; k < DIM; k++) {
        float a = zi[k];
        c0 = fmaf(a, znT[k * N2 + tid], c0);
        c1 = fmaf(a, znT[k * N2 + tid + BSZ], c1);
    }
    double Ereg = (tid == t) ? 0.0 : exp(-GAM * (2.0 - 2.0 * (double)c0));
    double kn2  = exp(-GAM * (2.0 - 2.0 * (double)c1));   // K[t, 320+tid]
    KnT[tid * BSZ + t] = kn2;                              // KnT[j][i] = K[i, 320+j]
    if (tid == t) posterm[t] = kn2;
    {
        double se = wave_red(Ereg);
        double sq = wave_red(Ereg * Ereg);
        if (lane == 0) { sred[wave][0] = se; sred[wave][1] = sq; }
        __syncthreads();
        if (tid == 0) {
            double a0 = 0, a1 = 0;
            for (int w = 0; w < 5; w++) { a0 += sred[w][0]; a1 += sred[w][1]; }
            rE[t] = a0; sc[0] = a0; sc[1] = a1;   // rEt, ssqt
        }
    }
    grid.sync();

    // ---------- Phase 3: per-t Woodbury + deletion coefficients ----------
    double rEi = rE[tid];
    {
        double s1 = wave_red(rEi);
        double s2 = wave_red(Ereg * rEi);
        if (lane == 0) { sred[wave][2] = s1; sred[wave][3] = s2; }
        __syncthreads();
        if (tid == 0) {
            double S = 0, mv = 0;
            for (int w = 0; w < 5; w++) { S += sred[w][2]; mv += sred[w][3]; }
            const double a = 1.0 / 1.1, c = 1.0 / 321.1;
            const double q = 1.0 - 320.0 * c;
            double rEt = sc[0], ssqt = sc[1];
            double pt  = a * q - a * a * q * (rEt - c * S);
            double b   = 320.0 * a * q - a * a * q * q * S;
            double up  = a * q * rEt - a * a * q * (mv - c * S * rEt);
            double sc1 = a * ssqt - a * c * rEt * rEt;
            double Wtt = -a * c * rEt;
            double Mtt = a * (1.0 - c) - a * a * (c * c * S - 2.0 * c * rEt);
            double s11 = 1.0 - up, s12 = -b, s21 = -sc1, s22 = 1.0 - up;
            double det = s11 * s22 - s12 * s21;
            double r1 = 2.0 * b, r2 = 2.0 * up;
            double be1 = (s22 * r1 - s12 * r2) / det;
            double be2 = (s11 * r2 - s21 * r1) / det;
            double g1  = (s22 * pt - s12 * Wtt) / det;
            double g2  = (s11 * Wtt - s21 * pt) / det;
            double ytt = 2.0 * pt + be1 * Wtt + be2 * pt;
            double dt  = Mtt + g1 * Wtt + g2 * pt;
            double rho = ytt / dt;
            sc[2] = 2.0 + be2 - rho * g2;   // cP
            sc[3] = be1 - rho * g1;         // cW
            sc[4] = -rho;                   // cM
            sc[5] = S;
        }
        __syncthreads();
    }

    // ---------- Phase 4: final per-(t,i) pass ----------
    {
        const double a = 1.0 / 1.1, c = 1.0 / 321.1;
        const double q = 1.0 - 320.0 * c;
        double S = sc[5], cP = sc[2], cW = sc[3], cM = sc[4], rEt = sc[0];
        double s_neg = 0, s_al = 0, s_kn = 0, cz = 0, c1v = 0, cpos = 0;
        if (tid != t) {
            double p_i = a * q - a * a * q * (rEi - c * S);
            double V   = a * Ereg - a * c * rEt;
            double Mi  = -a * c - a * a * (Ereg - c * (rEt + rEi) + c * c * S);
            double x = cP * p_i + cW * V + cM * Mi;
            double alpha = fmin(fmax(x, 0.0), 1.0);
            double kn = KnT[t * BSZ + tid];
            s_neg = alpha * kn; s_al = alpha; s_kn = kn;
            cz   = (x <= 0.0) ? 1.0 : 0.0;
            c1v  = (x >= 1.0) ? 1.0 : 0.0;
            cpos = (x > 0.0) ? 1.0 : 0.0;
        }
        s_neg = wave_red(s_neg); s_al = wave_red(s_al); s_kn = wave_red(s_kn);
        cz = wave_red(cz); c1v = wave_red(c1v); cpos = wave_red(cpos);
        if (lane == 0) {
            sred[wave][0] = s_neg; sred[wave][1] = s_al; sred[wave][2] = s_kn;
            sred[wave][3] = cz;    sred[wave][4] = c1v;  sred[wave][5] = cpos;
        }
        __syncthreads();
        if (tid == 0) {
            double a0 = 0, a1 = 0, a2 = 0, a3 = 0, a4 = 0, a5 = 0;
            for (int w = 0; w < 5; w++) {
                a0 += sred[w][0]; a1 += sred[w][1]; a2 += sred[w][2];
                a3 += sred[w][3]; a4 += sred[w][4]; a5 += sred[w][5];
            }
            partials[t * 6 + 0] = a0;
            partials[t * 6 + 1] = a1 * posterm[t];
            partials[t * 6 + 2] = a2;
            partials[t * 6 + 3] = a3;
            partials[t * 6 + 4] = a4;
            partials[t * 6 + 5] = a5;
        }
    }
    grid.sync();

    // ---------- Phase 5: block 0 reduces partials -> 6 f32 outputs ----------
    if (t == 0) {
        double s0 = partials[tid * 6 + 0], s1 = partials[tid * 6 + 1];
        double s2 = partials[tid * 6 + 2], s3 = partials[tid * 6 + 3];
        double s4 = partials[tid * 6 + 4], s5 = partials[tid * 6 + 5];
        double sp = posterm[tid];
        s0 = wave_red(s0); s1 = wave_red(s1); s2 = wave_red(s2);
        s3 = wave_red(s3); s4 = wave_red(s4); s5 = wave_red(s5);
        sp = wave_red(sp);
        if (lane == 0) {
            sred[wave][0] = s0; sred[wave][1] = s1; sred[wave][2] = s2;
            sred[wave][3] = s3; sred[wave][4] = s4; sred[wave][5] = s5;
            sred[wave][6] = sp;
        }
        __syncthreads();
        if (tid == 0) {
            double a0 = 0, a1 = 0, a2 = 0, a3 = 0, a4 = 0, a5 = 0, ap = 0;
            for (int w = 0; w < 5; w++) {
                a0 += sred[w][0]; a1 += sred[w][1]; a2 += sred[w][2];
                a3 += sred[w][3]; a4 += sred[w][4]; a5 += sred[w][5];
                ap += sred[w][6];
            }
            out[0] = (float)(a0 / 320.0 - a1 / 320.0);   // loss
            out[1] = (float)(ap / 320.0);                // pos_terms.mean()
            out[2] = (float)(a2 / (319.0 * 320.0));      // Kn.mean()
            out[3] = (float)(a4 / (a5 + 1e-10));         // sparsity
            out[4] = (float)(a3 / (320.0 * 319.0));      // num_zero
            out[5] = 0.0f;
        }
    }
}

extern "C" void kernel_launch(void* const* d_in, const int* in_sizes, int n_in,
                              void* d_out, int out_size, void* d_ws, size_t ws_size,
                              hipStream_t stream) {
    const float* z = (const float*)d_in[0];
    float* out = (float*)d_out;
    double* ws = (double*)d_ws;

    double* KnT      = ws;                 // 102400 f64
    double* rE       = KnT + 102400;       // 320
    double* posterm  = rE + 320;           // 320
    double* partials = posterm + 320;      // 1920
    float*  znT      = (float*)(partials + 1920);  // 81920 f32
    float*  znR      = znT + 81920;                // 81920 f32

    void* args[] = { (void*)&z, (void*)&znT, (void*)&znR, (void*)&KnT,
                     (void*)&rE, (void*)&posterm, (void*)&partials, (void*)&out };
    hipLaunchCooperativeKernel((void*)k_all, dim3(320), dim3(320), args, 0, stream);
}

// Round 4
// 61.586 us; speedup vs baseline: 2.2628x; 2.2628x over previous
//
#include <hip/hip_runtime.h>
#include <math.h>

#define BSZ 320
#define N2  640
#define DIM 128
#define GAM (1.0/0.07)
#define ROWS 2

__device__ __forceinline__ double wave_red(double v) {
    #pragma unroll
    for (int off = 32; off > 0; off >>= 1) v += __shfl_down(v, off, 64);
    return v;
}

// --- K1: fused norm + gram. Block handles rows i0,i0+1 of K (vs all 640 cols).
// Writes E (KK, zero diag), KnT, per-row stats rE/ssq. Block 0 zeroes accumulators. ---
__launch_bounds__(640)
__global__ void k_gram(const float* __restrict__ z, double* __restrict__ E,
                       double* __restrict__ KnT, double* __restrict__ rE,
                       double* __restrict__ ssq, double* __restrict__ acc,
                       int* __restrict__ counter) {
    const int j  = threadIdx.x;        // 640
    const int i0 = blockIdx.x * ROWS;  // 160 blocks
    __shared__ double sinv[N2];
    __shared__ float  zi[ROWS][DIM];
    __shared__ double sE[ROWS][10], sQ[ROWS][10];

    if (blockIdx.x == 0) {             // zero K2's accumulators (every call)
        if (j < 8) acc[j] = 0.0;
        if (j == 8) *counter = 0;
    }

    // each thread: inverse norm of its own row j
    {
        const float* zr = z + j * DIM;
        double s = 0.0;
        #pragma unroll 16
        for (int k = 0; k < DIM; k++) { double v = (double)zr[k]; s = fma(v, v, s); }
        sinv[j] = 1.0 / sqrt(s);
    }
    __syncthreads();
    if (j < ROWS * DIM) {
        int r = j >> 7, k = j & 127;
        zi[r][k] = (float)((double)z[(i0 + r) * DIM + k] * sinv[i0 + r]);
    }
    __syncthreads();

    float c0 = 0.f, c1 = 0.f;
    {
        const double invj = sinv[j];
        const float* zr = z + j * DIM;
        #pragma unroll 8
        for (int k = 0; k < DIM; k++) {
            float znj = (float)((double)zr[k] * invj);
            c0 = fmaf(zi[0][k], znj, c0);
            c1 = fmaf(zi[1][k], znj, c1);
        }
    }
    double v0 = exp(-GAM * (2.0 - 2.0 * (double)c0));
    double v1 = exp(-GAM * (2.0 - 2.0 * (double)c1));
    double e0 = 0.0, e1 = 0.0;
    if (j < BSZ) {
        e0 = (j == i0    ) ? 0.0 : v0;
        e1 = (j == i0 + 1) ? 0.0 : v1;
        E[(i0    ) * BSZ + j] = e0;
        E[(i0 + 1) * BSZ + j] = e1;
    } else {
        KnT[(j - BSZ) * BSZ + i0    ] = v0;   // KnT[j'][i] = K[i, 320+j']
        KnT[(j - BSZ) * BSZ + i0 + 1] = v1;
    }
    double q0 = e0 * e0, q1 = e1 * e1;
    e0 = wave_red(e0); q0 = wave_red(q0);
    e1 = wave_red(e1); q1 = wave_red(q1);
    int wave = j >> 6, lane = j & 63;
    if (lane == 0) { sE[0][wave] = e0; sQ[0][wave] = q0; sE[1][wave] = e1; sQ[1][wave] = q1; }
    __syncthreads();
    if (j < ROWS) {
        double se = 0.0, sq = 0.0;
        for (int w = 0; w < 10; w++) { se += sE[j][w]; sq += sQ[j][w]; }
        rE[i0 + j] = se; ssq[i0 + j] = sq;
    }
}

// --- K2: per-t coef + final pass + atomic global sums; last block writes outputs ---
__launch_bounds__(320)
__global__ void k_cf(const double* __restrict__ E, const double* __restrict__ KnT,
                     const double* __restrict__ rE, const double* __restrict__ ssq,
                     double* __restrict__ acc, int* __restrict__ counter,
                     float* __restrict__ out) {
    const int t = blockIdx.x, tid = threadIdx.x;   // 320 x 320
    const int wave = tid >> 6, lane = tid & 63;
    __shared__ double sred[5][6];
    __shared__ double sc[8];
    const double a = 1.0 / 1.1, c = 1.0 / 321.1;
    const double q = 1.0 - 320.0 * c;

    double rEi  = rE[tid];
    double Ereg = E[t * BSZ + tid];
    double kn   = KnT[t * BSZ + tid];
    if (tid == t) sc[6] = kn;                       // posterm_t = K[t, 320+t]

    // block reduce: S = sum rE, mv = E[t,:]. rE
    {
        double s1 = wave_red(rEi);
        double s2 = wave_red(Ereg * rEi);
        if (lane == 0) { sred[wave][0] = s1; sred[wave][1] = s2; }
    }
    __syncthreads();
    if (tid == 0) {
        double S = 0, mv = 0;
        for (int w = 0; w < 5; w++) { S += sred[w][0]; mv += sred[w][1]; }
        double rEt = rE[t], ssqt = ssq[t];
        double pt  = a * q - a * a * q * (rEt - c * S);
        double b   = 320.0 * a * q - a * a * q * q * S;
        double up  = a * q * rEt - a * a * q * (mv - c * S * rEt);
        double sc1 = a * ssqt - a * c * rEt * rEt;
        double Wtt = -a * c * rEt;
        double Mtt = a * (1.0 - c) - a * a * (c * c * S - 2.0 * c * rEt);
        double s11 = 1.0 - up, s12 = -b, s21 = -sc1, s22 = 1.0 - up;
        double det = s11 * s22 - s12 * s21;
        double r1 = 2.0 * b, r2 = 2.0 * up;
        double be1 = (s22 * r1 - s12 * r2) / det;
        double be2 = (s11 * r2 - s21 * r1) / det;
        double g1  = (s22 * pt - s12 * Wtt) / det;
        double g2  = (s11 * Wtt - s21 * pt) / det;
        double ytt = 2.0 * pt + be1 * Wtt + be2 * pt;
        double dt  = Mtt + g1 * Wtt + g2 * pt;
        double rho = ytt / dt;
        sc[0] = rEt;
        sc[1] = S;
        sc[2] = 2.0 + be2 - rho * g2;   // cP
        sc[3] = be1 - rho * g1;         // cW
        sc[4] = -rho;                   // cM
    }
    __syncthreads();

    // final per-(t, i=tid) pass
    {
        double rEt = sc[0], S = sc[1], cP = sc[2], cW = sc[3], cM = sc[4];
        double s_neg = 0, s_al = 0, s_kn = 0, cz = 0, c1v = 0, cpos = 0;
        if (tid != t) {
            double p_i = a * q - a * a * q * (rEi - c * S);
            double V   = a * Ereg - a * c * rEt;
            double Mi  = -a * c - a * a * (Ereg - c * (rEt + rEi) + c * c * S);
            double x = cP * p_i + cW * V + cM * Mi;
            double alpha = fmin(fmax(x, 0.0), 1.0);
            s_neg = alpha * kn; s_al = alpha; s_kn = kn;
            cz   = (x <= 0.0) ? 1.0 : 0.0;
            c1v  = (x >= 1.0) ? 1.0 : 0.0;
            cpos = (x > 0.0) ? 1.0 : 0.0;
        }
        s_neg = wave_red(s_neg); s_al = wave_red(s_al); s_kn = wave_red(s_kn);
        cz = wave_red(cz); c1v = wave_red(c1v); cpos = wave_red(cpos);
        if (lane == 0) {
            sred[wave][0] = s_neg; sred[wave][1] = s_al; sred[wave][2] = s_kn;
            sred[wave][3] = cz;    sred[wave][4] = c1v;  sred[wave][5] = cpos;
        }
    }
    __syncthreads();
    if (tid == 0) {
        double a0 = 0, a1 = 0, a2 = 0, a3 = 0, a4 = 0, a5 = 0;
        for (int w = 0; w < 5; w++) {
            a0 += sred[w][0]; a1 += sred[w][1]; a2 += sred[w][2];
            a3 += sred[w][3]; a4 += sred[w][4]; a5 += sred[w][5];
        }
        atomicAdd(&acc[0], a0);
        atomicAdd(&acc[1], a1 * sc[6]);
        atomicAdd(&acc[2], a2);
        atomicAdd(&acc[3], a3);
        atomicAdd(&acc[4], a4);
        atomicAdd(&acc[5], a5);
        atomicAdd(&acc[6], sc[6]);
        __threadfence();
        int ticket = atomicAdd(counter, 1);
        if (ticket == BSZ - 1) {
            double b0 = atomicAdd(&acc[0], 0.0);
            double b1 = atomicAdd(&acc[1], 0.0);
            double b2 = atomicAdd(&acc[2], 0.0);
            double b3 = atomicAdd(&acc[3], 0.0);
            double b4 = atomicAdd(&acc[4], 0.0);
            double b5 = atomicAdd(&acc[5], 0.0);
            double b6 = atomicAdd(&acc[6], 0.0);
            out[0] = (float)((b0 - b1) / 320.0);        // loss
            out[1] = (float)(b6 / 320.0);               // pos_terms.mean()
            out[2] = (float)(b2 / (319.0 * 320.0));     // Kn.mean()
            out[3] = (float)(b4 / (b5 + 1e-10));        // sparsity
            out[4] = (float)(b3 / (320.0 * 319.0));     // num_zero
            out[5] = 0.0f;
        }
    }
}

extern "C" void kernel_launch(void* const* d_in, const int* in_sizes, int n_in,
                              void* d_out, int out_size, void* d_ws, size_t ws_size,
                              hipStream_t stream) {
    const float* z = (const float*)d_in[0];
    float* out = (float*)d_out;
    double* ws = (double*)d_ws;

    double* E   = ws;                  // 102400 f64
    double* KnT = E + 102400;          // 102400 f64
    double* rE  = KnT + 102400;        // 320
    double* ssq = rE + 320;            // 320
    double* acc = ssq + 320;           // 8
    int* counter = (int*)(acc + 8);

    k_gram<<<dim3(BSZ / ROWS), dim3(640), 0, stream>>>(z, E, KnT, rE, ssq, acc, counter);
    k_cf  <<<dim3(BSZ), dim3(BSZ), 0, stream>>>(E, KnT, rE, ssq, acc, counter, out);
}

// Round 5
// 30.112 us; speedup vs baseline: 4.6280x; 2.0452x over previous
//
#include <hip/hip_runtime.h>
#include <math.h>

#define BSZ 320
#define N2  640
#define DIM 128
#define GAM (1.0/0.07)

__device__ __forceinline__ double wave_red(double v) {
    #pragma unroll
    for (int off = 32; off > 0; off >>= 1) v += __shfl_down(v, off, 64);
    return v;
}

// --- K1: fused norm + gram via LDS-staged z chunks (all loads coalesced).
// Block b owns rows i0=2b, i0+1. Writes E (=KK, zero diag), KnT, rE, ssq.
// Block 0 zeroes the ticket counter for K2. ---
__launch_bounds__(640)
__global__ void k_gram(const float* __restrict__ z, double* __restrict__ E,
                       double* __restrict__ KnT, double* __restrict__ rE,
                       double* __restrict__ ssq, int* __restrict__ counter) {
    const int j  = threadIdx.x;            // 640
    const int i0 = blockIdx.x * 2;         // 160 blocks
    __shared__ float  zc[N2][33];          // 32-k chunk of all 640 rows, padded
    __shared__ double sE[2][10], sQ[2][10];
    __shared__ double szi[2];

    if (blockIdx.x == 0 && j == 0) *counter = 0;

    double rr = 0.0;                       // own-row sum of squares (f64)
    float  cr0 = 0.f, cr1 = 0.f;           // raw dots vs rows i0, i0+1

    for (int kc = 0; kc < 4; kc++) {
        const int k0 = kc * 32;
        __syncthreads();                   // protect zc reuse
        // stage: 5120 float4s, linear assignment -> coalesced
        #pragma unroll
        for (int it = 0; it < 8; it++) {
            int f = it * 640 + j;          // 0..5119
            int row = f >> 3, c4 = f & 7;
            float4 v = *(const float4*)(z + row * DIM + k0 + c4 * 4);
            zc[row][c4 * 4 + 0] = v.x; zc[row][c4 * 4 + 1] = v.y;
            zc[row][c4 * 4 + 2] = v.z; zc[row][c4 * 4 + 3] = v.w;
        }
        __syncthreads();
        #pragma unroll
        for (int kk = 0; kk < 32; kk++) {
            float a0 = zc[i0][kk];         // broadcast
            float a1 = zc[i0 + 1][kk];     // broadcast
            float b  = zc[j][kk];          // 2-way bank alias (free)
            cr0 = fmaf(a0, b, cr0);
            cr1 = fmaf(a1, b, cr1);
            rr  = fma((double)b, (double)b, rr);
        }
    }

    double sinv = 1.0 / sqrt(rr);
    if (j == i0)     szi[0] = sinv;
    if (j == i0 + 1) szi[1] = sinv;
    __syncthreads();
    double c0 = (double)cr0 * szi[0] * sinv;
    double c1 = (double)cr1 * szi[1] * sinv;
    double v0 = exp(-GAM * (2.0 - 2.0 * c0));
    double v1 = exp(-GAM * (2.0 - 2.0 * c1));

    double e0 = 0.0, e1 = 0.0;
    if (j < BSZ) {
        e0 = (j == i0    ) ? 0.0 : v0;
        e1 = (j == i0 + 1) ? 0.0 : v1;
        E[(i0    ) * BSZ + j] = e0;
        E[(i0 + 1) * BSZ + j] = e1;
    } else {
        KnT[(j - BSZ) * BSZ + i0    ] = v0;   // KnT[j'][i] = K[i, 320+j']
        KnT[(j - BSZ) * BSZ + i0 + 1] = v1;
    }
    double q0 = e0 * e0, q1 = e1 * e1;
    e0 = wave_red(e0); q0 = wave_red(q0);
    e1 = wave_red(e1); q1 = wave_red(q1);
    int wave = j >> 6, lane = j & 63;
    if (lane == 0) { sE[0][wave] = e0; sQ[0][wave] = q0; sE[1][wave] = e1; sQ[1][wave] = q1; }
    __syncthreads();
    if (j < 2) {
        double se = 0.0, sq = 0.0;
        for (int w = 0; w < 10; w++) { se += sE[j][w]; sq += sQ[j][w]; }
        rE[i0 + j] = se; ssq[i0 + j] = sq;
    }
}

// --- K2: per-t coef + final pass; non-atomic partials + ticket; last block outputs ---
__launch_bounds__(320)
__global__ void k_cf(const double* __restrict__ E, const double* __restrict__ KnT,
                     const double* __restrict__ rE, const double* __restrict__ ssq,
                     double* __restrict__ partials, int* __restrict__ counter,
                     float* __restrict__ out) {
    const int t = blockIdx.x, tid = threadIdx.x;   // 320 x 320
    const int wave = tid >> 6, lane = tid & 63;
    __shared__ double sred[5][7];
    __shared__ double sc[8];
    __shared__ int lastflag;
    const double a = 1.0 / 1.1, c = 1.0 / 321.1;
    const double q = 1.0 - 320.0 * c;

    double rEi  = rE[tid];
    double Ereg = E[t * BSZ + tid];
    double kn   = KnT[t * BSZ + tid];
    if (tid == t) sc[6] = kn;                      // posterm_t = K[t, 320+t]

    // block reduce: S = sum rE, mv = E[t,:].rE
    {
        double s1 = wave_red(rEi);
        double s2 = wave_red(Ereg * rEi);
        if (lane == 0) { sred[wave][0] = s1; sred[wave][1] = s2; }
    }
    __syncthreads();
    if (tid == 0) {
        double S = 0, mv = 0;
        for (int w = 0; w < 5; w++) { S += sred[w][0]; mv += sred[w][1]; }
        double rEt = rE[t], ssqt = ssq[t];
        double pt  = a * q - a * a * q * (rEt - c * S);
        double b   = 320.0 * a * q - a * a * q * q * S;
        double up  = a * q * rEt - a * a * q * (mv - c * S * rEt);
        double sc1 = a * ssqt - a * c * rEt * rEt;
        double Wtt = -a * c * rEt;
        double Mtt = a * (1.0 - c) - a * a * (c * c * S - 2.0 * c * rEt);
        double s11 = 1.0 - up, s12 = -b, s21 = -sc1, s22 = 1.0 - up;
        double det = s11 * s22 - s12 * s21;
        double r1 = 2.0 * b, r2 = 2.0 * up;
        double be1 = (s22 * r1 - s12 * r2) / det;
        double be2 = (s11 * r2 - s21 * r1) / det;
        double g1  = (s22 * pt - s12 * Wtt) / det;
        double g2  = (s11 * Wtt - s21 * pt) / det;
        double ytt = 2.0 * pt + be1 * Wtt + be2 * pt;
        double dt  = Mtt + g1 * Wtt + g2 * pt;
        double rho = ytt / dt;
        sc[0] = rEt;
        sc[1] = S;
        sc[2] = 2.0 + be2 - rho * g2;   // cP
        sc[3] = be1 - rho * g1;         // cW
        sc[4] = -rho;                   // cM
    }
    __syncthreads();

    // final per-(t, i=tid) pass
    {
        double rEt = sc[0], S = sc[1], cP = sc[2], cW = sc[3], cM = sc[4];
        double s_neg = 0, s_al = 0, s_kn = 0, cz = 0, c1v = 0, cpos = 0;
        if (tid != t) {
            double p_i = a * q - a * a * q * (rEi - c * S);
            double V   = a * Ereg - a * c * rEt;
            double Mi  = -a * c - a * a * (Ereg - c * (rEt + rEi) + c * c * S);
            double x = cP * p_i + cW * V + cM * Mi;
            double alpha = fmin(fmax(x, 0.0), 1.0);
            s_neg = alpha * kn; s_al = alpha; s_kn = kn;
            cz   = (x <= 0.0) ? 1.0 : 0.0;
            c1v  = (x >= 1.0) ? 1.0 : 0.0;
            cpos = (x > 0.0) ? 1.0 : 0.0;
        }
        s_neg = wave_red(s_neg); s_al = wave_red(s_al); s_kn = wave_red(s_kn);
        cz = wave_red(cz); c1v = wave_red(c1v); cpos = wave_red(cpos);
        if (lane == 0) {
            sred[wave][0] = s_neg; sred[wave][1] = s_al; sred[wave][2] = s_kn;
            sred[wave][3] = cz;    sred[wave][4] = c1v;  sred[wave][5] = cpos;
        }
    }
    __syncthreads();
    if (tid == 0) {
        double a0 = 0, a1 = 0, a2 = 0, a3 = 0, a4 = 0, a5 = 0;
        for (int w = 0; w < 5; w++) {
            a0 += sred[w][0]; a1 += sred[w][1]; a2 += sred[w][2];
            a3 += sred[w][3]; a4 += sred[w][4]; a5 += sred[w][5];
        }
        partials[t * 8 + 0] = a0;
        partials[t * 8 + 1] = a1 * sc[6];
        partials[t * 8 + 2] = a2;
        partials[t * 8 + 3] = a3;
        partials[t * 8 + 4] = a4;
        partials[t * 8 + 5] = a5;
        partials[t * 8 + 6] = sc[6];
        __threadfence();
        int ticket = atomicAdd(counter, 1);
        lastflag = (ticket == BSZ - 1) ? 1 : 0;
    }
    __syncthreads();

    // last block: global reduce of partials -> 6 f32 outputs
    if (lastflag) {
        __threadfence();
        double v0 = partials[tid * 8 + 0], v1 = partials[tid * 8 + 1];
        double v2 = partials[tid * 8 + 2], v3 = partials[tid * 8 + 3];
        double v4 = partials[tid * 8 + 4], v5 = partials[tid * 8 + 5];
        double v6 = partials[tid * 8 + 6];
        v0 = wave_red(v0); v1 = wave_red(v1); v2 = wave_red(v2);
        v3 = wave_red(v3); v4 = wave_red(v4); v5 = wave_red(v5);
        v6 = wave_red(v6);
        if (lane == 0) {
            sred[wave][0] = v0; sred[wave][1] = v1; sred[wave][2] = v2;
            sred[wave][3] = v3; sred[wave][4] = v4; sred[wave][5] = v5;
            sred[wave][6] = v6;
        }
        __syncthreads();
        if (tid == 0) {
            double b0 = 0, b1 = 0, b2 = 0, b3 = 0, b4 = 0, b5 = 0, b6 = 0;
            for (int w = 0; w < 5; w++) {
                b0 += sred[w][0]; b1 += sred[w][1]; b2 += sred[w][2];
                b3 += sred[w][3]; b4 += sred[w][4]; b5 += sred[w][5];
                b6 += sred[w][6];
            }
            out[0] = (float)((b0 - b1) / 320.0);        // loss
            out[1] = (float)(b6 / 320.0);               // pos_terms.mean()
            out[2] = (float)(b2 / (319.0 * 320.0));     // Kn.mean()
            out[3] = (float)(b4 / (b5 + 1e-10));        // sparsity
            out[4] = (float)(b3 / (320.0 * 319.0));     // num_zero
            out[5] = 0.0f;
        }
    }
}

extern "C" void kernel_launch(void* const* d_in, const int* in_sizes, int n_in,
                              void* d_out, int out_size, void* d_ws, size_t ws_size,
                              hipStream_t stream) {
    const float* z = (const float*)d_in[0];
    float* out = (float*)d_out;
    double* ws = (double*)d_ws;

    double* E        = ws;                 // 102400 f64
    double* KnT      = E + 102400;         // 102400 f64
    double* rE       = KnT + 102400;       // 320
    double* ssq      = rE + 320;           // 320
    double* partials = ssq + 320;          // 320*8
    int* counter     = (int*)(partials + 320 * 8);

    k_gram<<<dim3(BSZ / 2), dim3(640), 0, stream>>>(z, E, KnT, rE, ssq, counter);
    k_cf  <<<dim3(BSZ), dim3(BSZ), 0, stream>>>(E, KnT, rE, ssq, partials, counter, out);
}

// Round 6
// 29.493 us; speedup vs baseline: 4.7251x; 1.0210x over previous
//
#include <hip/hip_runtime.h>
#include <math.h>

#define BSZ 320
#define N2  640
#define DIM 128
#define GAM (1.0/0.07)

__device__ __forceinline__ double wave_red(double v) {
    #pragma unroll
    for (int off = 32; off > 0; off >>= 1) v += __shfl_down(v, off, 64);
    return v;
}

// --- K1: fused norm + gram via LDS-staged z chunks; float4 (b128) LDS reads.
// Block b owns rows i0=2b, i0+1. Writes E (=KK, zero diag), KnT, rE, ssq.
// Block 0 zeroes the ticket counter for K2. ---
__launch_bounds__(640)
__global__ void k_gram(const float* __restrict__ z, double* __restrict__ E,
                       double* __restrict__ KnT, double* __restrict__ rE,
                       double* __restrict__ ssq, int* __restrict__ counter) {
    const int j  = threadIdx.x;            // 640
    const int i0 = blockIdx.x * 2;         // 160 blocks
    __shared__ float  zc[N2][36];          // 32-k chunk; stride 144B keeps rows 16B-aligned
    __shared__ double sE[2][10], sQ[2][10];
    __shared__ double szi[2];

    if (blockIdx.x == 0 && j == 0) *counter = 0;

    double rr = 0.0;                       // own-row sum of squares (f64)
    float  cr0 = 0.f, cr1 = 0.f;           // raw dots vs rows i0, i0+1

    for (int kc = 0; kc < 4; kc++) {
        const int k0 = kc * 32;
        __syncthreads();                   // protect zc reuse
        // stage: 5120 float4s, linear assignment -> coalesced global, clean LDS banks
        #pragma unroll
        for (int it = 0; it < 8; it++) {
            int f = it * 640 + j;          // 0..5119
            int row = f >> 3, c4 = f & 7;
            *(float4*)&zc[row][c4 * 4] = *(const float4*)(z + row * DIM + k0 + c4 * 4);
        }
        __syncthreads();
        #pragma unroll
        for (int k4 = 0; k4 < 8; k4++) {
            float4 b  = *(const float4*)&zc[j][k4 * 4];        // b128, ~2 words/bank/phase
            float4 a0 = *(const float4*)&zc[i0][k4 * 4];       // broadcast
            float4 a1 = *(const float4*)&zc[i0 + 1][k4 * 4];   // broadcast
            cr0 = fmaf(a0.x, b.x, cr0); cr1 = fmaf(a1.x, b.x, cr1);
            rr = fma((double)b.x, (double)b.x, rr);
            cr0 = fmaf(a0.y, b.y, cr0); cr1 = fmaf(a1.y, b.y, cr1);
            rr = fma((double)b.y, (double)b.y, rr);
            cr0 = fmaf(a0.z, b.z, cr0); cr1 = fmaf(a1.z, b.z, cr1);
            rr = fma((double)b.z, (double)b.z, rr);
            cr0 = fmaf(a0.w, b.w, cr0); cr1 = fmaf(a1.w, b.w, cr1);
            rr = fma((double)b.w, (double)b.w, rr);
        }
    }

    double sinv = 1.0 / sqrt(rr);
    if (j == i0)     szi[0] = sinv;
    if (j == i0 + 1) szi[1] = sinv;
    __syncthreads();
    double c0 = (double)cr0 * szi[0] * sinv;
    double c1 = (double)cr1 * szi[1] * sinv;
    double v0 = exp(-GAM * (2.0 - 2.0 * c0));
    double v1 = exp(-GAM * (2.0 - 2.0 * c1));

    double e0 = 0.0, e1 = 0.0;
    if (j < BSZ) {
        e0 = (j == i0    ) ? 0.0 : v0;
        e1 = (j == i0 + 1) ? 0.0 : v1;
        E[(i0    ) * BSZ + j] = e0;
        E[(i0 + 1) * BSZ + j] = e1;
    } else {
        KnT[(j - BSZ) * BSZ + i0    ] = v0;   // KnT[j'][i] = K[i, 320+j']
        KnT[(j - BSZ) * BSZ + i0 + 1] = v1;
    }
    double q0 = e0 * e0, q1 = e1 * e1;
    e0 = wave_red(e0); q0 = wave_red(q0);
    e1 = wave_red(e1); q1 = wave_red(q1);
    int wave = j >> 6, lane = j & 63;
    if (lane == 0) { sE[0][wave] = e0; sQ[0][wave] = q0; sE[1][wave] = e1; sQ[1][wave] = q1; }
    __syncthreads();
    if (j < 2) {
        double se = 0.0, sq = 0.0;
        for (int w = 0; w < 10; w++) { se += sE[j][w]; sq += sQ[j][w]; }
        rE[i0 + j] = se; ssq[i0 + j] = sq;
    }
}

// --- K2: per-t coef + final pass; non-atomic partials + ticket; last block outputs ---
__launch_bounds__(320)
__global__ void k_cf(const double* __restrict__ E, const double* __restrict__ KnT,
                     const double* __restrict__ rE, const double* __restrict__ ssq,
                     double* __restrict__ partials, int* __restrict__ counter,
                     float* __restrict__ out) {
    const int t = blockIdx.x, tid = threadIdx.x;   // 320 x 320
    const int wave = tid >> 6, lane = tid & 63;
    __shared__ double sred[5][7];
    __shared__ double sc[8];
    __shared__ int lastflag;
    const double a = 1.0 / 1.1, c = 1.0 / 321.1;
    const double q = 1.0 - 320.0 * c;

    double rEi  = rE[tid];
    double Ereg = E[t * BSZ + tid];
    double kn   = KnT[t * BSZ + tid];
    if (tid == t) sc[6] = kn;                      // posterm_t = K[t, 320+t]

    // block reduce: S = sum rE, mv = E[t,:].rE
    {
        double s1 = wave_red(rEi);
        double s2 = wave_red(Ereg * rEi);
        if (lane == 0) { sred[wave][0] = s1; sred[wave][1] = s2; }
    }
    __syncthreads();
    if (tid == 0) {
        double S = 0, mv = 0;
        for (int w = 0; w < 5; w++) { S += sred[w][0]; mv += sred[w][1]; }
        double rEt = rE[t], ssqt = ssq[t];
        double pt  = a * q - a * a * q * (rEt - c * S);
        double b   = 320.0 * a * q - a * a * q * q * S;
        double up  = a * q * rEt - a * a * q * (mv - c * S * rEt);
        double sc1 = a * ssqt - a * c * rEt * rEt;
        double Wtt = -a * c * rEt;
        double Mtt = a * (1.0 - c) - a * a * (c * c * S - 2.0 * c * rEt);
        double s11 = 1.0 - up, s12 = -b, s21 = -sc1, s22 = 1.0 - up;
        double det = s11 * s22 - s12 * s21;
        double r1 = 2.0 * b, r2 = 2.0 * up;
        double be1 = (s22 * r1 - s12 * r2) / det;
        double be2 = (s11 * r2 - s21 * r1) / det;
        double g1  = (s22 * pt - s12 * Wtt) / det;
        double g2  = (s11 * Wtt - s21 * pt) / det;
        double ytt = 2.0 * pt + be1 * Wtt + be2 * pt;
        double dt  = Mtt + g1 * Wtt + g2 * pt;
        double rho = ytt / dt;
        sc[0] = rEt;
        sc[1] = S;
        sc[2] = 2.0 + be2 - rho * g2;   // cP
        sc[3] = be1 - rho * g1;         // cW
        sc[4] = -rho;                   // cM
    }
    __syncthreads();

    // final per-(t, i=tid) pass
    {
        double rEt = sc[0], S = sc[1], cP = sc[2], cW = sc[3], cM = sc[4];
        double s_neg = 0, s_al = 0, s_kn = 0, cz = 0, c1v = 0, cpos = 0;
        if (tid != t) {
            double p_i = a * q - a * a * q * (rEi - c * S);
            double V   = a * Ereg - a * c * rEt;
            double Mi  = -a * c - a * a * (Ereg - c * (rEt + rEi) + c * c * S);
            double x = cP * p_i + cW * V + cM * Mi;
            double alpha = fmin(fmax(x, 0.0), 1.0);
            s_neg = alpha * kn; s_al = alpha; s_kn = kn;
            cz   = (x <= 0.0) ? 1.0 : 0.0;
            c1v  = (x >= 1.0) ? 1.0 : 0.0;
            cpos = (x > 0.0) ? 1.0 : 0.0;
        }
        s_neg = wave_red(s_neg); s_al = wave_red(s_al); s_kn = wave_red(s_kn);
        cz = wave_red(cz); c1v = wave_red(c1v); cpos = wave_red(cpos);
        if (lane == 0) {
            sred[wave][0] = s_neg; sred[wave][1] = s_al; sred[wave][2] = s_kn;
            sred[wave][3] = cz;    sred[wave][4] = c1v;  sred[wave][5] = cpos;
        }
    }
    __syncthreads();
    if (tid == 0) {
        double a0 = 0, a1 = 0, a2 = 0, a3 = 0, a4 = 0, a5 = 0;
        for (int w = 0; w < 5; w++) {
            a0 += sred[w][0]; a1 += sred[w][1]; a2 += sred[w][2];
            a3 += sred[w][3]; a4 += sred[w][4]; a5 += sred[w][5];
        }
        partials[t * 8 + 0] = a0;
        partials[t * 8 + 1] = a1 * sc[6];
        partials[t * 8 + 2] = a2;
        partials[t * 8 + 3] = a3;
        partials[t * 8 + 4] = a4;
        partials[t * 8 + 5] = a5;
        partials[t * 8 + 6] = sc[6];
        __threadfence();
        int ticket = atomicAdd(counter, 1);
        lastflag = (ticket == BSZ - 1) ? 1 : 0;
    }
    __syncthreads();

    // last block: global reduce of partials -> 6 f32 outputs
    if (lastflag) {
        __threadfence();
        double v0 = partials[tid * 8 + 0], v1 = partials[tid * 8 + 1];
        double v2 = partials[tid * 8 + 2], v3 = partials[tid * 8 + 3];
        double v4 = partials[tid * 8 + 4], v5 = partials[tid * 8 + 5];
        double v6 = partials[tid * 8 + 6];
        v0 = wave_red(v0); v1 = wave_red(v1); v2 = wave_red(v2);
        v3 = wave_red(v3); v4 = wave_red(v4); v5 = wave_red(v5);
        v6 = wave_red(v6);
        if (lane == 0) {
            sred[wave][0] = v0; sred[wave][1] = v1; sred[wave][2] = v2;
            sred[wave][3] = v3; sred[wave][4] = v4; sred[wave][5] = v5;
            sred[wave][6] = v6;
        }
        __syncthreads();
        if (tid == 0) {
            double b0 = 0, b1 = 0, b2 = 0, b3 = 0, b4 = 0, b5 = 0, b6 = 0;
            for (int w = 0; w < 5; w++) {
                b0 += sred[w][0]; b1 += sred[w][1]; b2 += sred[w][2];
                b3 += sred[w][3]; b4 += sred[w][4]; b5 += sred[w][5];
                b6 += sred[w][6];
            }
            out[0] = (float)((b0 - b1) / 320.0);        // loss
            out[1] = (float)(b6 / 320.0);               // pos_terms.mean()
            out[2] = (float)(b2 / (319.0 * 320.0));     // Kn.mean()
            out[3] = (float)(b4 / (b5 + 1e-10));        // sparsity
            out[4] = (float)(b3 / (320.0 * 319.0));     // num_zero
            out[5] = 0.0f;
        }
    }
}

extern "C" void kernel_launch(void* const* d_in, const int* in_sizes, int n_in,
                              void* d_out, int out_size, void* d_ws, size_t ws_size,
                              hipStream_t stream) {
    const float* z = (const float*)d_in[0];
    float* out = (float*)d_out;
    double* ws = (double*)d_ws;

    double* E        = ws;                 // 102400 f64
    double* KnT      = E + 102400;         // 102400 f64
    double* rE       = KnT + 102400;       // 320
    double* ssq      = rE + 320;           // 320
    double* partials = ssq + 320;          // 320*8
    int* counter     = (int*)(partials + 320 * 8);

    k_gram<<<dim3(BSZ / 2), dim3(640), 0, stream>>>(z, E, KnT, rE, ssq, counter);
    k_cf  <<<dim3(BSZ), dim3(BSZ), 0, stream>>>(E, KnT, rE, ssq, partials, counter, out);
}